// Round 1
// baseline (161.779 us; speedup 1.0000x reference)
//
#include <hip/hip_runtime.h>
#include <math.h>

#define HH 96
#define WW 96
#define CC 64
#define BBATCH 4
#define PLANE (HH * WW)          // 9216
#define NPLANES (BBATCH * CC)    // 256
#define NPIX (NPLANES * PLANE)   // 2359296
#define NPC (BBATCH * PLANE)     // per-channel element count 36864
#define CHUNKS 4
#define PER_CHUNK (PLANE / CHUNKS) // 2304
#define BLOCK 256

// Knots: t[i] = (i-3)*0.4 - 1.0, i = 0..11  (12 knots, uniform spacing h=0.4)
// Degree-3 Cox-de Boor -> 8 basis functions, matching reference _b_splines.

__global__ __launch_bounds__(BLOCK) void kconv_stage1(
    const float* __restrict__ x,
    const float* __restrict__ base_w,     // (9,)
    const float* __restrict__ spline_w,   // (9,8)
    const float* __restrict__ spline_s,   // (9,)
    float* __restrict__ y,                // (B,C,H,W) pre-BN output
    float* __restrict__ stats)            // [0..63] sum, [64..127] sumsq
{
    __shared__ float s_bw[9];
    __shared__ float s_sw[72];

    const int tid = threadIdx.x;
    if (tid < 72) s_sw[tid] = spline_w[tid] * spline_s[tid >> 3];
    if (tid < 9)  s_bw[tid] = base_w[tid];
    __syncthreads();

    const int plane = blockIdx.x;   // b*C + c
    const int chunk = blockIdx.y;
    const float* xp = x + (size_t)plane * PLANE;
    float* yp = y + (size_t)plane * PLANE;

    // knots (compiler constant-folds)
    float t[12];
#pragma unroll
    for (int i = 0; i < 12; ++i) t[i] = (float)(i - 3) * 0.4f - 1.0f;
    // reciprocal denominators for levels k=1..3 (uniform spacing k*h)
    const float inv1 = 1.0f / 0.4f;
    const float inv2 = 1.0f / 0.8f;
    const float inv3 = 1.0f / 1.2f;

    float lsum = 0.0f, lsumsq = 0.0f;

    const int lo = chunk * PER_CHUNK;
    const int hi = lo + PER_CHUNK;
    for (int i = lo + tid; i < hi; i += BLOCK) {
        const int h = i / WW;
        const int w = i - h * WW;

        float acc = 0.0f;
#pragma unroll
        for (int dh = -1; dh <= 1; ++dh) {
#pragma unroll
            for (int dw = -1; dw <= 1; ++dw) {
                const int hh = h + dh;
                const int ww = w + dw;
                float v = 0.0f;
                if (hh >= 0 && hh < HH && ww >= 0 && ww < WW)
                    v = xp[hh * WW + ww];
                const int j = (dh + 1) * 3 + (dw + 1);

                // SiLU base path
                acc += s_bw[j] * (v / (1.0f + expf(-v)));

                // B-spline path: degree-0 indicators then 3 recursion levels
                float b[11];
#pragma unroll
                for (int q = 0; q < 11; ++q)
                    b[q] = (v >= t[q] && v < t[q + 1]) ? 1.0f : 0.0f;
                // k = 1 -> 10 entries
#pragma unroll
                for (int q = 0; q < 10; ++q)
                    b[q] = (v - t[q]) * inv1 * b[q] + (t[q + 2] - v) * inv1 * b[q + 1];
                // k = 2 -> 9 entries
#pragma unroll
                for (int q = 0; q < 9; ++q)
                    b[q] = (v - t[q]) * inv2 * b[q] + (t[q + 3] - v) * inv2 * b[q + 1];
                // k = 3 -> 8 entries
#pragma unroll
                for (int q = 0; q < 8; ++q)
                    b[q] = (v - t[q]) * inv3 * b[q] + (t[q + 4] - v) * inv3 * b[q + 1];

#pragma unroll
                for (int q = 0; q < 8; ++q)
                    acc += b[q] * s_sw[j * 8 + q];
            }
        }

        yp[i] = acc;
        lsum += acc;
        lsumsq += acc * acc;
    }

    // wave (64) reduction then cross-wave via LDS
#pragma unroll
    for (int off = 32; off > 0; off >>= 1) {
        lsum   += __shfl_down(lsum, off, 64);
        lsumsq += __shfl_down(lsumsq, off, 64);
    }
    __shared__ float red_s[4], red_q[4];
    const int wave = tid >> 6;
    if ((tid & 63) == 0) { red_s[wave] = lsum; red_q[wave] = lsumsq; }
    __syncthreads();
    if (tid == 0) {
        float s = red_s[0] + red_s[1] + red_s[2] + red_s[3];
        float q = red_q[0] + red_q[1] + red_q[2] + red_q[3];
        const int c = plane & (CC - 1);
        atomicAdd(&stats[c], s);
        atomicAdd(&stats[CC + c], q);
    }
}

__global__ __launch_bounds__(BLOCK) void kconv_stage2(
    float* __restrict__ y,
    const float* __restrict__ stats,
    const float* __restrict__ gamma,
    const float* __restrict__ beta)
{
    const int i = blockIdx.x * BLOCK + threadIdx.x;
    if (i >= NPIX) return;
    const int c = (i / PLANE) & (CC - 1);
    const float inv_n = 1.0f / (float)NPC;
    const float mean = stats[c] * inv_n;
    const float var  = stats[CC + c] * inv_n - mean * mean;
    const float scale = rsqrtf(var + 1e-5f) * gamma[c];
    const float v = (y[i] - mean) * scale + beta[c];
    y[i] = fmaxf(v, 0.0f);
}

extern "C" void kernel_launch(void* const* d_in, const int* in_sizes, int n_in,
                              void* d_out, int out_size, void* d_ws, size_t ws_size,
                              hipStream_t stream)
{
    const float* x        = (const float*)d_in[0];
    const float* base_w   = (const float*)d_in[1];
    const float* spline_w = (const float*)d_in[2];
    const float* spline_s = (const float*)d_in[3];
    const float* gamma    = (const float*)d_in[4];
    const float* beta     = (const float*)d_in[5];
    float* out   = (float*)d_out;
    float* stats = (float*)d_ws;

    // ws is re-poisoned to 0xAA before every timed launch -> zero the stats each call
    hipMemsetAsync(stats, 0, 2 * CC * sizeof(float), stream);

    dim3 g1(NPLANES, CHUNKS);
    kconv_stage1<<<g1, BLOCK, 0, stream>>>(x, base_w, spline_w, spline_s, out, stats);

    kconv_stage2<<<(NPIX + BLOCK - 1) / BLOCK, BLOCK, 0, stream>>>(out, stats, gamma, beta);
}

// Round 2
// 90.682 us; speedup vs baseline: 1.7840x; 1.7840x over previous
//
#include <hip/hip_runtime.h>
#include <math.h>

#define HH 96
#define WW 96
#define CC 64
#define BB 4
#define PLANE (HH * WW)          // 9216
#define NPLANES (BB * CC)        // 256
#define NPC (BB * PLANE)         // 36864 per-channel count
#define TILE 32
#define TPL 3                    // 96/32 tiles per axis
#define NTILES (TPL * TPL)       // 9
#define HALO 34
#define HALO_N (HALO * HALO)     // 1156
#define BLOCK 256

// Uniform knots t[i] = (i-3)*0.4 - 1.0, i=0..11. For v in interval p
// (t[p] <= v < t[p+1]), the degree-3 truncated Cox-de-Boor result equals the
// standard uniform cubic B-spline with basis indices {p-3..p} clipped to [0,7].
// Per (feature j, interval p) this is a cubic in u = (v - t[p])/h, so we build
// a 9 x 13 table of Horner coefficients (p = -1 and p = 11 rows are zero,
// handling |v| beyond the knot span).

__global__ __launch_bounds__(BLOCK) void kconv_stage1(
    const float* __restrict__ x,
    const float* __restrict__ base_w,     // (9,)
    const float* __restrict__ spline_w,   // (9,8)
    const float* __restrict__ spline_s,   // (9,)
    float* __restrict__ y,                // pre-BN output (B,C,H,W)
    float2* __restrict__ part)            // (NPLANES*NTILES) partial (sum, sumsq)
{
    __shared__ float4 s_c[9 * 13];
    __shared__ float  s_bw[9];
    __shared__ float2 s_g[HALO_N];        // (silu(v), knot coord s)

    const int tid = threadIdx.x;

    // Build the per-(j, interval) cubic coefficient table.
    if (tid < 9 * 13) {
        const int j  = tid / 13;
        const int ip = tid - j * 13;
        const int p  = ip - 1;            // interval in [-1, 11]
        const float sc = spline_s[j];
        float w[4];
#pragma unroll
        for (int r = 0; r < 4; ++r) {
            const int q = p - 3 + r;
            w[r] = (q >= 0 && q < 8) ? spline_w[j * 8 + q] * sc : 0.0f;
        }
        float4 c;
        c.x = (w[0] + 4.0f * w[1] + w[2]) * (1.0f / 6.0f);
        c.y = (w[2] - w[0]) * 0.5f;
        c.z = (w[0] - 2.0f * w[1] + w[2]) * 0.5f;
        c.w = (w[3] - w[0]) * (1.0f / 6.0f) + (w[1] - w[2]) * 0.5f;
        s_c[tid] = c;
    }
    if (tid < 9) s_bw[tid] = base_w[tid];

    const int plane = blockIdx.z;
    const int h0 = blockIdx.y * TILE;
    const int w0 = blockIdx.x * TILE;
    const float* xp = x + (size_t)plane * PLANE;

    // Stage halo: per input pixel compute silu(v) and clamped knot coordinate.
    for (int i = tid; i < HALO_N; i += BLOCK) {
        const int hy = i / HALO;
        const int hx = i - hy * HALO;
        const int gh = h0 + hy - 1;
        const int gw = w0 + hx - 1;
        float v = 0.0f;
        if (gh >= 0 && gh < HH && gw >= 0 && gw < WW) v = xp[gh * WW + gw];
        const float e = __expf(-v);
        const float silu = v * __builtin_amdgcn_rcpf(1.0f + e);
        float s = (v + 2.2f) * 2.5f;
        s = fminf(fmaxf(s, -0.5f), 11.5f);
        s_g[i] = make_float2(silu, s);
    }
    __syncthreads();

    const int tx  = tid & 31;
    const int ty4 = (tid >> 5) * 4;       // 4 vertically-adjacent rows per thread

    float lsum = 0.0f, lsq = 0.0f;
    float* yp = y + (size_t)plane * PLANE + (size_t)h0 * WW + w0;

#pragma unroll
    for (int k = 0; k < 4; ++k) {
        const int ty = ty4 + k;
        float acc = 0.0f;
#pragma unroll
        for (int dh = 0; dh < 3; ++dh) {
#pragma unroll
            for (int dw = 0; dw < 3; ++dw) {
                const int j = dh * 3 + dw;
                const float2 g = s_g[(ty + dh) * HALO + (tx + dw)];
                acc = fmaf(s_bw[j], g.x, acc);
                const float pf = floorf(g.y);
                const float u  = g.y - pf;
                const int  ipv = (int)pf + 1;
                const float4 c = s_c[j * 13 + ipv];
                float t = fmaf(c.w, u, c.z);
                t = fmaf(t, u, c.y);
                t = fmaf(t, u, c.x);
                acc += t;
            }
        }
        yp[ty * WW + tx] = acc;
        lsum += acc;
        lsq = fmaf(acc, acc, lsq);
    }

    // wave then cross-wave reduction -> one partial per block (no atomics)
#pragma unroll
    for (int off = 32; off; off >>= 1) {
        lsum += __shfl_down(lsum, off, 64);
        lsq  += __shfl_down(lsq,  off, 64);
    }
    __shared__ float2 red[4];
    if ((tid & 63) == 0) red[tid >> 6] = make_float2(lsum, lsq);
    __syncthreads();
    if (tid == 0) {
        const float s = red[0].x + red[1].x + red[2].x + red[3].x;
        const float q = red[0].y + red[1].y + red[2].y + red[3].y;
        part[plane * NTILES + blockIdx.y * TPL + blockIdx.x] = make_float2(s, q);
    }
}

__global__ __launch_bounds__(BLOCK) void kconv_stage2(
    float* __restrict__ y,
    const float2* __restrict__ part,
    const float* __restrict__ gamma,
    const float* __restrict__ beta)
{
    __shared__ float2 sb;
    const int tid = threadIdx.x;
    const int plane = blockIdx.x;
    const int c = plane & (CC - 1);

    if (tid < 64) {
        float s = 0.0f, q = 0.0f;
        if (tid < 36) {
            const int b = tid / 9;
            const int t = tid - b * 9;
            const float2 pp = part[(c + CC * b) * NTILES + t];
            s = pp.x; q = pp.y;
        }
#pragma unroll
        for (int off = 32; off; off >>= 1) {
            s += __shfl_down(s, off, 64);
            q += __shfl_down(q, off, 64);
        }
        if (tid == 0) {
            const float inv = 1.0f / (float)NPC;
            const float mean = s * inv;
            const float var  = q * inv - mean * mean;
            const float sc   = rsqrtf(var + 1e-5f) * gamma[c];
            sb = make_float2(sc, beta[c] - mean * sc);
        }
    }
    __syncthreads();
    const float2 sbv = sb;

    float4* yp = (float4*)(y + (size_t)plane * PLANE + (size_t)blockIdx.y * 1024);
    float4 v = yp[tid];
    v.x = fmaxf(fmaf(v.x, sbv.x, sbv.y), 0.0f);
    v.y = fmaxf(fmaf(v.y, sbv.x, sbv.y), 0.0f);
    v.z = fmaxf(fmaf(v.z, sbv.x, sbv.y), 0.0f);
    v.w = fmaxf(fmaf(v.w, sbv.x, sbv.y), 0.0f);
    yp[tid] = v;
}

extern "C" void kernel_launch(void* const* d_in, const int* in_sizes, int n_in,
                              void* d_out, int out_size, void* d_ws, size_t ws_size,
                              hipStream_t stream)
{
    const float* x        = (const float*)d_in[0];
    const float* base_w   = (const float*)d_in[1];
    const float* spline_w = (const float*)d_in[2];
    const float* spline_s = (const float*)d_in[3];
    const float* gamma    = (const float*)d_in[4];
    const float* beta     = (const float*)d_in[5];
    float* out   = (float*)d_out;
    float2* part = (float2*)d_ws;   // 2304 float2, written before read each call

    dim3 g1(TPL, TPL, NPLANES);
    kconv_stage1<<<g1, BLOCK, 0, stream>>>(x, base_w, spline_w, spline_s, out, part);

    dim3 g2(NPLANES, PLANE / (BLOCK * 4));  // (256, 9)
    kconv_stage2<<<g2, BLOCK, 0, stream>>>(out, part, gamma, beta);
}

// Round 3
// 86.605 us; speedup vs baseline: 1.8680x; 1.0471x over previous
//
#include <hip/hip_runtime.h>
#include <math.h>

#define HH 96
#define WW 96
#define CC 64
#define BB 4
#define PLANE (HH * WW)          // 9216
#define NPLANES (BB * CC)        // 256
#define NPC (BB * PLANE)         // 36864 per-channel count
#define TILE 32
#define TPL 3
#define NTILES (TPL * TPL)       // 9
#define HALO 34
#define HALO_N (HALO * HALO)     // 1156
#define BLOCK 256

typedef _Float16 h2v __attribute__((ext_vector_type(2)));

static __device__ __forceinline__ float dot2h(unsigned a, unsigned b, float c) {
#if __has_builtin(__builtin_amdgcn_fdot2)
    return __builtin_amdgcn_fdot2(__builtin_bit_cast(h2v, a),
                                  __builtin_bit_cast(h2v, b), c, false);
#else
    h2v x = __builtin_bit_cast(h2v, a);
    h2v y = __builtin_bit_cast(h2v, b);
    return c + (float)x[0] * (float)y[0] + (float)x[1] * (float)y[1];
#endif
}

static __device__ __forceinline__ unsigned pk16(float a, float b) {
    return __builtin_bit_cast(unsigned, __builtin_amdgcn_cvt_pkrtz(a, b));
}

// Uniform cubic B-spline: knots t[i]=(i-3)*0.4-1.0. In knot coords
// sigma=(v+2.2)*2.5, basis N_q (q=0..7) is nonzero only for q=p-3..p where
// p=floor(sigma); the 4 values are B0..B3(u), feature-independent. We build
// the full 8-slot fp16 N-vector per input pixel by shifting (B0..B3) into
// slots p-3..p (out-of-range slots drop out => matches truncated recursion).

__global__ __launch_bounds__(BLOCK) void kconv_stage1(
    const float* __restrict__ x,
    const float* __restrict__ base_w,     // (9,)
    const float* __restrict__ spline_w,   // (9,8)
    const float* __restrict__ spline_s,   // (9,)
    float* __restrict__ y,
    float2* __restrict__ part)
{
    __shared__ uint4  s_n[HALO_N];        // packed fp16 N8 per halo cell
    __shared__ float  s_sl[HALO_N];       // silu per halo cell
    __shared__ unsigned s_wp[36];         // fp16 weight pairs, 9 feats x 4
    __shared__ float  s_bw[9];

    const int tid = threadIdx.x;

    if (tid < 36) {
        const int j = tid >> 2;
        const int k = tid & 3;
        const float sc = spline_s[j];
        const float w0 = spline_w[j * 8 + 2 * k]     * sc;
        const float w1 = spline_w[j * 8 + 2 * k + 1] * sc;
        s_wp[tid] = pk16(w0, w1);
    }
    if (tid < 9) s_bw[tid] = base_w[tid];

    const int plane = blockIdx.z;
    const int h0 = blockIdx.y * TILE;
    const int w0 = blockIdx.x * TILE;
    const float* xp = x + (size_t)plane * PLANE;

    for (int i = tid; i < HALO_N; i += BLOCK) {
        const int hy = i / HALO;
        const int hx = i - hy * HALO;
        const int gh = h0 + hy - 1;
        const int gw = w0 + hx - 1;
        float v = 0.0f;
        if (gh >= 0 && gh < HH && gw >= 0 && gw < WW) v = xp[gh * WW + gw];

        const float e  = __expf(-v);
        const float sl = v * __builtin_amdgcn_rcpf(1.0f + e);

        // sigma' = sigma - 3 so floor gives t = p-3 directly
        const float sp = fmaf(v, 2.5f, 2.5f);
        const float tf = floorf(sp);
        const float u  = sp - tf;
        const int   t  = (int)tf;
        const int   m  = t >> 1;          // floor(t/2)
        const bool  odd = (t & 1) != 0;

        const float w1m = 1.0f - u;
        const float u2 = u * u;
        const float u3 = u2 * u;
        const float B0 = w1m * w1m * (w1m * (1.0f / 6.0f));
        const float B3 = u2 * (u * (1.0f / 6.0f));
        const float B1 = fmaf(-u2, 1.0f, fmaf(u3, 0.5f, 2.0f / 3.0f));
        const float B2 = 1.0f - B0 - B1 - B3;

        const unsigned h01 = pk16(B0, B1);
        const unsigned h23 = pk16(B2, B3);

        unsigned n[4];
        unsigned a_prev;
        {
            const int k0 = -1 - m;
            a_prev = (k0 == 0) ? h01 : ((k0 == 1) ? h23 : 0u);
        }
#pragma unroll
        for (int d = 0; d < 4; ++d) {
            const int k0 = d - m;
            const unsigned a_cur = (k0 == 0) ? h01 : ((k0 == 1) ? h23 : 0u);
            const unsigned sh = __builtin_amdgcn_alignbit(a_cur, a_prev, 16);
            n[d] = odd ? sh : a_cur;
            a_prev = a_cur;
        }

        s_n[i]  = make_uint4(n[0], n[1], n[2], n[3]);
        s_sl[i] = sl;
    }
    __syncthreads();

    // uniforms -> SGPRs
    unsigned wp[36];
    float bw[9];
#pragma unroll
    for (int q = 0; q < 36; ++q)
        wp[q] = __builtin_amdgcn_readfirstlane(s_wp[q]);
#pragma unroll
    for (int q = 0; q < 9; ++q)
        bw[q] = __int_as_float(__builtin_amdgcn_readfirstlane(__float_as_int(s_bw[q])));

    const int tx  = tid & 31;
    const int ty4 = (tid >> 5) * 4;

    float acc[4] = {0.0f, 0.0f, 0.0f, 0.0f};

    // roll over 6 halo rows; each cell read exactly once
#pragma unroll
    for (int r = 0; r < 6; ++r) {
        const int base = (ty4 + r) * HALO + tx;
        uint4 cn[3];
        float cs[3];
#pragma unroll
        for (int dw = 0; dw < 3; ++dw) {
            cn[dw] = s_n[base + dw];
            cs[dw] = s_sl[base + dw];
        }
#pragma unroll
        for (int k = 0; k < 4; ++k) {
            const int dh = r - k;
            if (dh >= 0 && dh < 3) {
#pragma unroll
                for (int dw = 0; dw < 3; ++dw) {
                    const int j = dh * 3 + dw;
                    float a = acc[k];
                    a = dot2h(cn[dw].x, wp[j * 4 + 0], a);
                    a = dot2h(cn[dw].y, wp[j * 4 + 1], a);
                    a = dot2h(cn[dw].z, wp[j * 4 + 2], a);
                    a = dot2h(cn[dw].w, wp[j * 4 + 3], a);
                    a = fmaf(bw[j], cs[dw], a);
                    acc[k] = a;
                }
            }
        }
    }

    float lsum = 0.0f, lsq = 0.0f;
    float* yp = y + (size_t)plane * PLANE + (size_t)h0 * WW + w0;
#pragma unroll
    for (int k = 0; k < 4; ++k) {
        yp[(ty4 + k) * WW + tx] = acc[k];
        lsum += acc[k];
        lsq = fmaf(acc[k], acc[k], lsq);
    }

#pragma unroll
    for (int off = 32; off; off >>= 1) {
        lsum += __shfl_down(lsum, off, 64);
        lsq  += __shfl_down(lsq,  off, 64);
    }
    __shared__ float2 red[4];
    if ((tid & 63) == 0) red[tid >> 6] = make_float2(lsum, lsq);
    __syncthreads();
    if (tid == 0) {
        const float s = red[0].x + red[1].x + red[2].x + red[3].x;
        const float q = red[0].y + red[1].y + red[2].y + red[3].y;
        part[plane * NTILES + blockIdx.y * TPL + blockIdx.x] = make_float2(s, q);
    }
}

__global__ __launch_bounds__(BLOCK) void kconv_stage2(
    float* __restrict__ y,
    const float2* __restrict__ part,
    const float* __restrict__ gamma,
    const float* __restrict__ beta)
{
    __shared__ float2 sb;
    const int tid = threadIdx.x;
    const int plane = blockIdx.x;
    const int c = plane & (CC - 1);

    if (tid < 64) {
        float s = 0.0f, q = 0.0f;
        if (tid < 36) {
            const int b = tid / 9;
            const int t = tid - b * 9;
            const float2 pp = part[(c + CC * b) * NTILES + t];
            s = pp.x; q = pp.y;
        }
#pragma unroll
        for (int off = 32; off; off >>= 1) {
            s += __shfl_down(s, off, 64);
            q += __shfl_down(q, off, 64);
        }
        if (tid == 0) {
            const float inv = 1.0f / (float)NPC;
            const float mean = s * inv;
            const float var  = q * inv - mean * mean;
            const float sc   = rsqrtf(var + 1e-5f) * gamma[c];
            sb = make_float2(sc, beta[c] - mean * sc);
        }
    }
    __syncthreads();
    const float2 sbv = sb;

    float4* yp = (float4*)(y + (size_t)plane * PLANE + (size_t)blockIdx.y * 1024);
    float4 v = yp[tid];
    v.x = fmaxf(fmaf(v.x, sbv.x, sbv.y), 0.0f);
    v.y = fmaxf(fmaf(v.y, sbv.x, sbv.y), 0.0f);
    v.z = fmaxf(fmaf(v.z, sbv.x, sbv.y), 0.0f);
    v.w = fmaxf(fmaf(v.w, sbv.x, sbv.y), 0.0f);
    yp[tid] = v;
}

extern "C" void kernel_launch(void* const* d_in, const int* in_sizes, int n_in,
                              void* d_out, int out_size, void* d_ws, size_t ws_size,
                              hipStream_t stream)
{
    const float* x        = (const float*)d_in[0];
    const float* base_w   = (const float*)d_in[1];
    const float* spline_w = (const float*)d_in[2];
    const float* spline_s = (const float*)d_in[3];
    const float* gamma    = (const float*)d_in[4];
    const float* beta     = (const float*)d_in[5];
    float* out   = (float*)d_out;
    float2* part = (float2*)d_ws;

    dim3 g1(TPL, TPL, NPLANES);
    kconv_stage1<<<g1, BLOCK, 0, stream>>>(x, base_w, spline_w, spline_s, out, part);

    dim3 g2(NPLANES, PLANE / (BLOCK * 4));
    kconv_stage2<<<g2, BLOCK, 0, stream>>>(out, part, gamma, beta);
}

// Round 4
// 86.227 us; speedup vs baseline: 1.8762x; 1.0044x over previous
//
#include <hip/hip_runtime.h>
#include <math.h>

#define HH 96
#define WW 96
#define CC 64
#define BB 4
#define PLANE (HH * WW)          // 9216
#define NPLANES (BB * CC)        // 256
#define NPC (BB * PLANE)         // 36864 per-channel count
#define TILE 32
#define TPL 3
#define NTILES (TPL * TPL)       // 9
#define HALO 34
#define HALO_N (HALO * HALO)     // 1156
#define BLOCK 256

typedef _Float16 h2v __attribute__((ext_vector_type(2)));

static __device__ __forceinline__ float dot2h(unsigned a, unsigned b, float c) {
#if __has_builtin(__builtin_amdgcn_fdot2)
    return __builtin_amdgcn_fdot2(__builtin_bit_cast(h2v, a),
                                  __builtin_bit_cast(h2v, b), c, false);
#else
    h2v x = __builtin_bit_cast(h2v, a);
    h2v y = __builtin_bit_cast(h2v, b);
    return c + (float)x[0] * (float)y[0] + (float)x[1] * (float)y[1];
#endif
}

static __device__ __forceinline__ unsigned pk16(float a, float b) {
    return __builtin_bit_cast(unsigned, __builtin_amdgcn_cvt_pkrtz(a, b));
}

// One block per (plane, h-strip); each block sweeps 3 horizontal 32x32 tiles.
// 768 blocks total = exactly 3 per CU (LDS 23.1KB -> 6 fit) -> single
// dispatch round, balanced tail.

__global__ __launch_bounds__(BLOCK) void kconv_stage1(
    const float* __restrict__ x,
    const float* __restrict__ base_w,
    const float* __restrict__ spline_w,   // (9,8)
    const float* __restrict__ spline_s,   // (9,)
    float* __restrict__ y,
    float2* __restrict__ part)
{
    __shared__ uint4  s_n[HALO_N];        // packed fp16 N8 per halo cell
    __shared__ float  s_sl[HALO_N];       // silu per halo cell
    __shared__ unsigned s_wp[36];
    __shared__ float  s_bw[9];
    __shared__ float2 red[4];

    const int tid = threadIdx.x;

    if (tid < 36) {
        const int j = tid >> 2;
        const int k = tid & 3;
        const float sc = spline_s[j];
        s_wp[tid] = pk16(spline_w[j * 8 + 2 * k] * sc,
                         spline_w[j * 8 + 2 * k + 1] * sc);
    }
    if (tid < 9) s_bw[tid] = base_w[tid];

    const int plane = blockIdx.y;
    const int h0 = blockIdx.x * TILE;
    const float* xp = x + (size_t)plane * PLANE;

    // precompute halo cell coords for this thread's 5 slots
    int hy[5], hx[5];
#pragma unroll
    for (int s = 0; s < 5; ++s) {
        const int i = tid + s * BLOCK;
        const int r = i / HALO;
        hy[s] = r;
        hx[s] = i - r * HALO;
    }

    const int tx  = tid & 31;
    const int ty4 = (tid >> 5) * 4;

    for (int wt = 0; wt < TPL; ++wt) {
        const int w0 = wt * TILE;

        // ---- phase A: prefetch all halo x values (independent loads) ----
        float v[5];
#pragma unroll
        for (int s = 0; s < 5; ++s) {
            const int gh = h0 + hy[s] - 1;
            const int gw = w0 + hx[s] - 1;
            const bool ok = (tid + s * BLOCK < HALO_N) &&
                            gh >= 0 && gh < HH && gw >= 0 && gw < WW;
            v[s] = ok ? xp[gh * WW + gw] : 0.0f;
        }

        if (wt == 0) __syncthreads();     // weight staging visible

        // ---- phase B: per-cell silu + shifted fp16 basis vector ----
#pragma unroll
        for (int s = 0; s < 5; ++s) {
            const int i = tid + s * BLOCK;
            if (i >= HALO_N) break;
            const float vv = v[s];
            const float e  = __expf(-vv);
            const float sl = vv * __builtin_amdgcn_rcpf(1.0f + e);

            const float sp = fmaf(vv, 2.5f, 2.5f);   // sigma - 3
            const float tf = floorf(sp);
            const float u  = sp - tf;
            const int   t  = (int)tf;
            const int   m  = t >> 1;
            const bool  odd = (t & 1) != 0;

            const float w1m = 1.0f - u;
            const float u2 = u * u;
            const float u3 = u2 * u;
            const float B0 = w1m * w1m * (w1m * (1.0f / 6.0f));
            const float B3 = u2 * (u * (1.0f / 6.0f));
            const float B1 = fmaf(-u2, 1.0f, fmaf(u3, 0.5f, 2.0f / 3.0f));
            const float B2 = 1.0f - B0 - B1 - B3;

            const unsigned h01 = pk16(B0, B1);
            const unsigned h23 = pk16(B2, B3);

            unsigned n[4];
            unsigned a_prev;
            {
                const int k0 = -1 - m;
                a_prev = (k0 == 0) ? h01 : ((k0 == 1) ? h23 : 0u);
            }
#pragma unroll
            for (int d = 0; d < 4; ++d) {
                const int k0 = d - m;
                const unsigned a_cur = (k0 == 0) ? h01 : ((k0 == 1) ? h23 : 0u);
                const unsigned sh = __builtin_amdgcn_alignbit(a_cur, a_prev, 16);
                n[d] = odd ? sh : a_cur;
                a_prev = a_cur;
            }
            s_n[i]  = make_uint4(n[0], n[1], n[2], n[3]);
            s_sl[i] = sl;
        }
        __syncthreads();

        // uniforms -> SGPRs
        unsigned wp[36];
        float bw[9];
#pragma unroll
        for (int q = 0; q < 36; ++q)
            wp[q] = __builtin_amdgcn_readfirstlane(s_wp[q]);
#pragma unroll
        for (int q = 0; q < 9; ++q)
            bw[q] = __int_as_float(__builtin_amdgcn_readfirstlane(__float_as_int(s_bw[q])));

        // ---- phase C: main compute, roll over 6 halo rows ----
        float acc[4] = {0.0f, 0.0f, 0.0f, 0.0f};
#pragma unroll
        for (int r = 0; r < 6; ++r) {
            const int base = (ty4 + r) * HALO + tx;
            uint4 cn[3];
            float cs[3];
#pragma unroll
            for (int dw = 0; dw < 3; ++dw) {
                cn[dw] = s_n[base + dw];
                cs[dw] = s_sl[base + dw];
            }
#pragma unroll
            for (int k = 0; k < 4; ++k) {
                const int dh = r - k;
                if (dh >= 0 && dh < 3) {
#pragma unroll
                    for (int dw = 0; dw < 3; ++dw) {
                        const int j = dh * 3 + dw;
                        float a = acc[k];
                        a = dot2h(cn[dw].x, wp[j * 4 + 0], a);
                        a = dot2h(cn[dw].y, wp[j * 4 + 1], a);
                        a = dot2h(cn[dw].z, wp[j * 4 + 2], a);
                        a = dot2h(cn[dw].w, wp[j * 4 + 3], a);
                        a = fmaf(bw[j], cs[dw], a);
                        acc[k] = a;
                    }
                }
            }
        }

        float lsum = 0.0f, lsq = 0.0f;
        float* yp = y + (size_t)plane * PLANE + (size_t)h0 * WW + w0;
#pragma unroll
        for (int k = 0; k < 4; ++k) {
            yp[(ty4 + k) * WW + tx] = acc[k];
            lsum += acc[k];
            lsq = fmaf(acc[k], acc[k], lsq);
        }

#pragma unroll
        for (int off = 32; off; off >>= 1) {
            lsum += __shfl_down(lsum, off, 64);
            lsq  += __shfl_down(lsq,  off, 64);
        }
        if ((tid & 63) == 0) red[tid >> 6] = make_float2(lsum, lsq);
        __syncthreads();   // red visible; also protects s_n reuse next tile
        if (tid == 0) {
            const float s = red[0].x + red[1].x + red[2].x + red[3].x;
            const float q = red[0].y + red[1].y + red[2].y + red[3].y;
            part[plane * NTILES + blockIdx.x * TPL + wt] = make_float2(s, q);
        }
    }
}

__global__ __launch_bounds__(BLOCK) void kconv_stage2(
    float* __restrict__ y,
    const float2* __restrict__ part,
    const float* __restrict__ gamma,
    const float* __restrict__ beta)
{
    __shared__ float2 sb;
    const int tid = threadIdx.x;
    const int plane = blockIdx.x;
    const int c = plane & (CC - 1);

    if (tid < 64) {
        float s = 0.0f, q = 0.0f;
        if (tid < 36) {
            const int b = tid / 9;
            const int t = tid - b * 9;
            const float2 pp = part[(c + CC * b) * NTILES + t];
            s = pp.x; q = pp.y;
        }
#pragma unroll
        for (int off = 32; off; off >>= 1) {
            s += __shfl_down(s, off, 64);
            q += __shfl_down(q, off, 64);
        }
        if (tid == 0) {
            const float inv = 1.0f / (float)NPC;
            const float mean = s * inv;
            const float var  = q * inv - mean * mean;
            const float sc   = rsqrtf(var + 1e-5f) * gamma[c];
            sb = make_float2(sc, beta[c] - mean * sc);
        }
    }
    __syncthreads();
    const float2 sbv = sb;

    float4* yp = (float4*)(y + (size_t)plane * PLANE + (size_t)blockIdx.y * 1024);
    float4 v = yp[tid];
    v.x = fmaxf(fmaf(v.x, sbv.x, sbv.y), 0.0f);
    v.y = fmaxf(fmaf(v.y, sbv.x, sbv.y), 0.0f);
    v.z = fmaxf(fmaf(v.z, sbv.x, sbv.y), 0.0f);
    v.w = fmaxf(fmaf(v.w, sbv.x, sbv.y), 0.0f);
    yp[tid] = v;
}

extern "C" void kernel_launch(void* const* d_in, const int* in_sizes, int n_in,
                              void* d_out, int out_size, void* d_ws, size_t ws_size,
                              hipStream_t stream)
{
    const float* x        = (const float*)d_in[0];
    const float* base_w   = (const float*)d_in[1];
    const float* spline_w = (const float*)d_in[2];
    const float* spline_s = (const float*)d_in[3];
    const float* gamma    = (const float*)d_in[4];
    const float* beta     = (const float*)d_in[5];
    float* out   = (float*)d_out;
    float2* part = (float2*)d_ws;

    dim3 g1(TPL, NPLANES);   // 768 blocks = 3 per CU
    kconv_stage1<<<g1, BLOCK, 0, stream>>>(x, base_w, spline_w, spline_s, out, part);

    dim3 g2(NPLANES, PLANE / (BLOCK * 4));
    kconv_stage2<<<g2, BLOCK, 0, stream>>>(out, part, gamma, beta);
}